// Round 6
// baseline (54.944 us; speedup 1.0000x reference)
//
#include <hip/hip_runtime.h>

// loss = (dot(x[0:half], x[half:n]) / rows + 1) / 2, rows = half/1024.
// Row-major => sum_i dot(real_i, fake_i) is a flat dot of the two halves.
//
// R6: fused last-block finalize with CHEAP agent-scope atomics.
// R2's failure was __threadfence() per block (full L2 writeback storm).
// Here: partial published via relaxed agent atomic store (single sc1
// write-through store), s_waitcnt 0, relaxed agent atomicAdd ticket.
// Last block reads partials with agent-scope atomic loads (cache-bypass,
// immune to stale L2 lines from previous replays), fixed summation order
// -> bitwise deterministic. Counter zeroed via 4-byte memset node each call
// (correctness call runs with arbitrary ws contents).

constexpr int BLOCK = 256;
constexpr int GRID  = 2048;   // 256 CUs x 8 blocks co-resident

__global__ __launch_bounds__(BLOCK) void dot_fused_kernel(
    const float4* __restrict__ a, const float4* __restrict__ b,
    float* __restrict__ partials, unsigned int* __restrict__ counter,
    float* __restrict__ out, long n4, float inv_count)
{
    const long tid    = (long)blockIdx.x * BLOCK + threadIdx.x;
    const long stride = (long)GRID * BLOCK;

    float acc0 = 0.f, acc1 = 0.f, acc2 = 0.f, acc3 = 0.f;
    long i = tid;
    for (; i + 3 * stride < n4; i += 4 * stride) {
        float4 x0 = a[i];              float4 y0 = b[i];
        float4 x1 = a[i + stride];     float4 y1 = b[i + stride];
        float4 x2 = a[i + 2 * stride]; float4 y2 = b[i + 2 * stride];
        float4 x3 = a[i + 3 * stride]; float4 y3 = b[i + 3 * stride];
        acc0 += x0.x * y0.x + x0.y * y0.y + x0.z * y0.z + x0.w * y0.w;
        acc1 += x1.x * y1.x + x1.y * y1.y + x1.z * y1.z + x1.w * y1.w;
        acc2 += x2.x * y2.x + x2.y * y2.y + x2.z * y2.z + x2.w * y2.w;
        acc3 += x3.x * y3.x + x3.y * y3.y + x3.z * y3.z + x3.w * y3.w;
    }
    for (; i < n4; i += stride) {   // tail (empty at the bench shape)
        float4 x = a[i]; float4 y = b[i];
        acc0 += x.x * y.x + x.y * y.y + x.z * y.z + x.w * y.w;
    }
    float acc = (acc0 + acc1) + (acc2 + acc3);

    #pragma unroll
    for (int off = 32; off > 0; off >>= 1)
        acc += __shfl_down(acc, off, 64);

    __shared__ float s[BLOCK / 64];
    __shared__ bool  is_last;
    const int lane = threadIdx.x & 63;
    const int wave = threadIdx.x >> 6;
    if (lane == 0) s[wave] = acc;
    __syncthreads();

    if (threadIdx.x == 0) {
        float p = (s[0] + s[1]) + (s[2] + s[3]);
        // write-through publish (single store, no cache flush)
        __hip_atomic_store(&partials[blockIdx.x], p,
                           __ATOMIC_RELAXED, __HIP_MEMORY_SCOPE_AGENT);
        __builtin_amdgcn_s_waitcnt(0);   // partial visible before ticket
        unsigned int prev = __hip_atomic_fetch_add(
            counter, 1u, __ATOMIC_RELAXED, __HIP_MEMORY_SCOPE_AGENT);
        is_last = (prev == (unsigned int)(GRID - 1));
    }
    __syncthreads();
    if (!is_last) return;

    // Last block: read all partials with cache-bypassing agent loads.
    float f = 0.f;
    #pragma unroll
    for (int k = 0; k < GRID / BLOCK; ++k)
        f += __hip_atomic_load(&partials[k * BLOCK + threadIdx.x],
                               __ATOMIC_RELAXED, __HIP_MEMORY_SCOPE_AGENT);
    #pragma unroll
    for (int off = 32; off > 0; off >>= 1)
        f += __shfl_down(f, off, 64);
    if (lane == 0) s[wave] = f;
    __syncthreads();
    if (threadIdx.x == 0)
        out[0] = (((s[0] + s[1]) + (s[2] + s[3])) * inv_count + 1.0f) * 0.5f;
}

extern "C" void kernel_launch(void* const* d_in, const int* in_sizes, int n_in,
                              void* d_out, int out_size, void* d_ws, size_t ws_size,
                              hipStream_t stream) {
    const float* x = (const float*)d_in[0];
    long n    = (long)in_sizes[0];   // 65536 * 1024
    long half = n / 2;
    long n4   = half / 4;
    long rows = half / 1024;

    const float4* a = (const float4*)x;
    const float4* b = (const float4*)(x + half);

    float* partials       = (float*)d_ws;
    unsigned int* counter = (unsigned int*)((char*)d_ws + GRID * sizeof(float));

    hipMemsetAsync(counter, 0, sizeof(unsigned int), stream);
    dot_fused_kernel<<<GRID, BLOCK, 0, stream>>>(
        a, b, partials, counter, (float*)d_out, n4, 1.0f / (float)rows);
}